// Round 2
// baseline (3338.553 us; speedup 1.0000x reference)
//
#include <hip/hip_runtime.h>

// ---------------------------------------------------------------------------
// JonbertaSelfAttention fused pipeline, MI355X gfx950.   DEBUG BISECTION ROUND:
// attention replaced by trivially-correct per-thread online-softmax kernels.
// B=4 S=1024 DM=1024 H=16 D=64 SE=512 DF=512 MAXP=1024
// Pipeline: convert(fp32->bf16) -> 5x MFMA GEMM (q,k,v,fk,fv)
//   -> slow self-attn (band bias, per-thread) -> slow enc-attn (+add, ->bf16)
//   -> out-proj GEMM (+bias+residual) -> LayerNorm
// ---------------------------------------------------------------------------

typedef unsigned short u16;
typedef __attribute__((ext_vector_type(8))) short bf16x8;
typedef __attribute__((ext_vector_type(4))) float f32x4;

#define DEV static __device__ __forceinline__

constexpr int H_ = 16;

DEV u16 f2bf(float f) {
  unsigned u = __float_as_uint(f);
  unsigned r = (u + 0x7FFFu + ((u >> 16) & 1u)) >> 16;  // RNE
  return (u16)r;
}
DEV unsigned pack2(float a, float b) {
  return (unsigned)f2bf(a) | ((unsigned)f2bf(b) << 16);
}
DEV float bf2f(u16 u) { return __uint_as_float(((unsigned)u) << 16); }
DEV f32x4 mfma16(bf16x8 a, bf16x8 b, f32x4 c) {
  return __builtin_amdgcn_mfma_f32_16x16x32_bf16(a, b, c, 0, 0, 0);
}

// ---------------------------------------------------------------------------
// fp32 -> bf16 conversion of all inputs (hardcoded segment table).
// ---------------------------------------------------------------------------
__global__ __launch_bounds__(256) void k_convert(
    const float* __restrict__ hs, const float* __restrict__ enc,
    const float* __restrict__ wq, const float* __restrict__ wk,
    const float* __restrict__ wv, const float* __restrict__ wo,
    const float* __restrict__ wfk, const float* __restrict__ wfv,
    const float* __restrict__ de,
    u16* __restrict__ o_hs, u16* __restrict__ o_enc, u16* __restrict__ o_wq,
    u16* __restrict__ o_wk, u16* __restrict__ o_wv, u16* __restrict__ o_wo,
    u16* __restrict__ o_wfk, u16* __restrict__ o_wfv, u16* __restrict__ o_e) {
  long i = ((long)blockIdx.x * 256 + threadIdx.x) * 4;
  const float* s; u16* d; long base; bool isE = false;
  if (i < 4194304L)        { s = hs;  d = o_hs;  base = 0L; }
  else if (i < 5242880L)   { s = enc; d = o_enc; base = 4194304L; }
  else if (i < 6291456L)   { s = wq;  d = o_wq;  base = 5242880L; }
  else if (i < 7340032L)   { s = wk;  d = o_wk;  base = 6291456L; }
  else if (i < 8388608L)   { s = wv;  d = o_wv;  base = 7340032L; }
  else if (i < 9437184L)   { s = wo;  d = o_wo;  base = 8388608L; }
  else if (i < 9961472L)   { s = wfk; d = o_wfk; base = 9437184L; }
  else if (i < 10485760L)  { s = wfv; d = o_wfv; base = 9961472L; }
  else                     { s = de;  d = o_e;   base = 10485760L; isE = true; }
  long li = i - base;
  uint2 o;
  if (isE && li >= 131008L) {
    o.x = 0u; o.y = 0u;  // zero-pad dist_emb to 2048 rows
  } else {
    float4 v = *(const float4*)(s + li);
    o.x = pack2(v.x, v.y);
    o.y = pack2(v.z, v.w);
  }
  *(uint2*)(d + li) = o;
}

// ---------------------------------------------------------------------------
// bf16 GEMM: C[m,n] = sum_k A[m,k]*W[n,k] + bias[n]  (torch Linear)
// 128x128 tile, BK=32, 4 waves (64x64 each, 4x4 16x16x32 MFMA frags).
// OMODE 0: bf16 out scattered [B,H,Sdim,64]
// OMODE 2: f32  out flat [M,N] = acc + bias + resid
// ---------------------------------------------------------------------------
template <int OMODE>
__global__ __launch_bounds__(256) void k_gemm(
    const u16* __restrict__ A, const u16* __restrict__ W,
    const float* __restrict__ bias, void* __restrict__ out,
    const float* __restrict__ resid, int M, int N, int K, int Sdim,
    int sdbits) {
  __shared__ u16 As[128 * 40];
  __shared__ u16 Bs[128 * 40];
  int t = threadIdx.x, w = t >> 6, lane = t & 63;
  int m0 = blockIdx.y * 128, n0 = blockIdx.x * 128;
  int wrow = (w >> 1) * 64, wcol = (w & 1) * 64;
  f32x4 acc[4][4] = {};
  int rs = 32 * w + (lane >> 2);
  int cs = (lane & 3) * 8;
  int nkt = K >> 5;
  for (int kt = 0; kt < nkt; kt++) {
    int k0 = kt << 5;
    bf16x8 ra0 = *(const bf16x8*)(A + (long)(m0 + rs) * K + k0 + cs);
    bf16x8 ra1 = *(const bf16x8*)(A + (long)(m0 + rs + 16) * K + k0 + cs);
    bf16x8 rb0 = *(const bf16x8*)(W + (long)(n0 + rs) * K + k0 + cs);
    bf16x8 rb1 = *(const bf16x8*)(W + (long)(n0 + rs + 16) * K + k0 + cs);
    __syncthreads();
    *(bf16x8*)(As + rs * 40 + cs) = ra0;
    *(bf16x8*)(As + (rs + 16) * 40 + cs) = ra1;
    *(bf16x8*)(Bs + rs * 40 + cs) = rb0;
    *(bf16x8*)(Bs + (rs + 16) * 40 + cs) = rb1;
    __syncthreads();
    bf16x8 af[4], bfr[4];
#pragma unroll
    for (int mi = 0; mi < 4; mi++)
      af[mi] = *(const bf16x8*)(As + (wrow + mi * 16 + (lane & 15)) * 40 +
                                8 * (lane >> 4));
#pragma unroll
    for (int ni = 0; ni < 4; ni++)
      bfr[ni] = *(const bf16x8*)(Bs + (wcol + ni * 16 + (lane & 15)) * 40 +
                                 8 * (lane >> 4));
#pragma unroll
    for (int mi = 0; mi < 4; mi++)
#pragma unroll
      for (int ni = 0; ni < 4; ni++)
        acc[mi][ni] = mfma16(af[mi], bfr[ni], acc[mi][ni]);
  }
#pragma unroll
  for (int mi = 0; mi < 4; mi++) {
#pragma unroll
    for (int ni = 0; ni < 4; ni++) {
      int col = n0 + wcol + ni * 16 + (lane & 15);
      float bcol = bias[col];
#pragma unroll
      for (int e = 0; e < 4; e++) {
        int grow = m0 + wrow + mi * 16 + (lane >> 4) * 4 + e;
        float val = acc[mi][ni][e] + bcol;
        if (OMODE == 2) {
          long idx = (long)grow * N + col;
          ((float*)out)[idx] = val + resid[idx];
        } else {
          int bb = grow >> sdbits, sloc = grow & (Sdim - 1);
          int hh = col >> 6, dd = col & 63;
          long idx = ((long)(bb * H_ + hh) * Sdim + sloc) * 64 + dd;
          ((u16*)out)[idx] = f2bf(val);
        }
      }
    }
  }
}

// ---------------------------------------------------------------------------
// SLOW self-attention: one thread per (b,h,query l). Online softmax over all
// 1024 keys with relative-position band bias. Trivially correct reference.
// k/v row addresses are block-uniform -> broadcast loads; E rows coalesced.
// ---------------------------------------------------------------------------
__global__ __launch_bounds__(256) void k_attn_slow_self(
    const u16* __restrict__ qg, const u16* __restrict__ kg,
    const u16* __restrict__ vg, const u16* __restrict__ eg,
    const float* __restrict__ maskg, float* __restrict__ ctx_f32) {
  int bh = blockIdx.y, bb = bh >> 4, h = bh & 15;
  int l = blockIdx.x * 256 + threadIdx.x;
  const u16* qp = qg + ((long)bh * 1024 + l) * 64;
  float q[64];
#pragma unroll
  for (int d = 0; d < 64; d += 8) {
    bf16x8 v8 = *(const bf16x8*)(qp + d);
#pragma unroll
    for (int j = 0; j < 8; j++) q[d + j] = bf2f((u16)v8[j]);
  }
  const float* mp = maskg + bb * 1024;
  float m = -1e30f, s = 0.f, ctx[64];
#pragma unroll
  for (int d = 0; d < 64; d++) ctx[d] = 0.f;
  for (int r = 0; r < 1024; r++) {
    const u16* kp = kg + ((long)bh * 1024 + r) * 64;
    const u16* ep = eg + (long)(l - r + 1023) * 64;
    float sqk = 0.f, sqe = 0.f, ske = 0.f;
#pragma unroll
    for (int d = 0; d < 64; d += 8) {
      bf16x8 k8 = *(const bf16x8*)(kp + d);
      bf16x8 e8 = *(const bf16x8*)(ep + d);
#pragma unroll
      for (int j = 0; j < 8; j++) {
        float kd = bf2f((u16)k8[j]), ed = bf2f((u16)e8[j]);
        sqk += q[d + j] * kd;
        sqe += q[d + j] * ed;
        ske += kd * ed;
      }
    }
    float sc = (sqk + sqe + ske) * 0.125f + mp[r];
    float mn = fmaxf(m, sc);
    float al = __expf(m - mn), p = __expf(sc - mn);
    m = mn;
    s = s * al + p;
    const u16* vp = vg + ((long)bh * 1024 + r) * 64;
#pragma unroll
    for (int d = 0; d < 64; d += 8) {
      bf16x8 v8 = *(const bf16x8*)(vp + d);
#pragma unroll
      for (int j = 0; j < 8; j++)
        ctx[d + j] = ctx[d + j] * al + p * bf2f((u16)v8[j]);
    }
  }
  float is = 1.f / s;
  long obase = ((long)bb * 1024 + l) * 1024 + h * 64;
#pragma unroll
  for (int d = 0; d < 64; d++) ctx_f32[obase + d] = ctx[d] * is;
}

// ---------------------------------------------------------------------------
// SLOW encoder cross-attention: adds into self-attn ctx, emits bf16.
// ---------------------------------------------------------------------------
__global__ __launch_bounds__(256) void k_attn_slow_enc(
    const u16* __restrict__ qg, const u16* __restrict__ fkg,
    const u16* __restrict__ fvg, const float* __restrict__ ctx_in,
    u16* __restrict__ ctx_bf) {
  int bh = blockIdx.y, bb = bh >> 4, h = bh & 15;
  int l = blockIdx.x * 256 + threadIdx.x;
  const u16* qp = qg + ((long)bh * 1024 + l) * 64;
  float q[64];
#pragma unroll
  for (int d = 0; d < 64; d += 8) {
    bf16x8 v8 = *(const bf16x8*)(qp + d);
#pragma unroll
    for (int j = 0; j < 8; j++) q[d + j] = bf2f((u16)v8[j]);
  }
  float m = -1e30f, s = 0.f, ctx[64];
#pragma unroll
  for (int d = 0; d < 64; d++) ctx[d] = 0.f;
  for (int r = 0; r < 512; r++) {
    const u16* kp = fkg + ((long)bh * 512 + r) * 64;
    float sqk = 0.f;
#pragma unroll
    for (int d = 0; d < 64; d += 8) {
      bf16x8 k8 = *(const bf16x8*)(kp + d);
#pragma unroll
      for (int j = 0; j < 8; j++) sqk += q[d + j] * bf2f((u16)k8[j]);
    }
    float sc = sqk * 0.125f;
    float mn = fmaxf(m, sc);
    float al = __expf(m - mn), p = __expf(sc - mn);
    m = mn;
    s = s * al + p;
    const u16* vp = fvg + ((long)bh * 512 + r) * 64;
#pragma unroll
    for (int d = 0; d < 64; d += 8) {
      bf16x8 v8 = *(const bf16x8*)(vp + d);
#pragma unroll
      for (int j = 0; j < 8; j++)
        ctx[d + j] = ctx[d + j] * al + p * bf2f((u16)v8[j]);
    }
  }
  float is = 1.f / s;
  long obase = ((long)bb * 1024 + l) * 1024 + h * 64;
#pragma unroll
  for (int d = 0; d < 64; d++)
    ctx_bf[obase + d] = f2bf(ctx[d] * is + ctx_in[obase + d]);
}

// ---------------------------------------------------------------------------
// Row LayerNorm: 1 block per row of y[4096][1024].
// ---------------------------------------------------------------------------
__global__ __launch_bounds__(256) void k_ln(const float* __restrict__ y,
                                            const float* __restrict__ g,
                                            const float* __restrict__ bta,
                                            float* __restrict__ out) {
  int row = blockIdx.x, t = threadIdx.x;
  const float* yr = y + (long)row * 1024;
  float4 v = *(const float4*)(yr + t * 4);
  float s = v.x + v.y + v.z + v.w;
  float q = v.x * v.x + v.y * v.y + v.z * v.z + v.w * v.w;
#pragma unroll
  for (int off = 1; off < 64; off <<= 1) {
    s += __shfl_xor(s, off);
    q += __shfl_xor(q, off);
  }
  __shared__ float ss[4], qq[4];
  if ((t & 63) == 0) {
    ss[t >> 6] = s;
    qq[t >> 6] = q;
  }
  __syncthreads();
  s = ss[0] + ss[1] + ss[2] + ss[3];
  q = qq[0] + qq[1] + qq[2] + qq[3];
  float mu = s * (1.f / 1024.f);
  float var = q * (1.f / 1024.f) - mu * mu;
  float rinv = rsqrtf(var + 1e-12f);
  float4 gv = *(const float4*)(g + t * 4);
  float4 bv = *(const float4*)(bta + t * 4);
  float4 o;
  o.x = (v.x - mu) * rinv * gv.x + bv.x;
  o.y = (v.y - mu) * rinv * gv.y + bv.y;
  o.z = (v.z - mu) * rinv * gv.z + bv.z;
  o.w = (v.w - mu) * rinv * gv.w + bv.w;
  *(float4*)(out + (long)row * 1024 + t * 4) = o;
}

// ---------------------------------------------------------------------------
extern "C" void kernel_launch(void* const* d_in, const int* in_sizes, int n_in,
                              void* d_out, int out_size, void* d_ws,
                              size_t ws_size, hipStream_t stream) {
  (void)in_sizes; (void)n_in; (void)out_size; (void)ws_size;
  const float* hs   = (const float*)d_in[0];
  const float* mask = (const float*)d_in[1];
  const float* enc  = (const float*)d_in[2];
  const float* Wq   = (const float*)d_in[3];
  const float* bq   = (const float*)d_in[4];
  const float* Wk   = (const float*)d_in[5];
  const float* bk   = (const float*)d_in[6];
  const float* Wv   = (const float*)d_in[7];
  const float* bv   = (const float*)d_in[8];
  const float* Wfk  = (const float*)d_in[9];
  const float* bfk  = (const float*)d_in[10];
  const float* Wfv  = (const float*)d_in[11];
  const float* bfv  = (const float*)d_in[12];
  const float* de   = (const float*)d_in[13];
  const float* Wo   = (const float*)d_in[14];
  const float* bo   = (const float*)d_in[15];
  const float* lng  = (const float*)d_in[16];
  const float* lnb  = (const float*)d_in[17];

  char* ws = (char*)d_ws;
  // Compact layout (63.2 MB total). ctx1/y alias the first 16 MB, which holds
  // hs_bf/enc_bf/wq/wk/wv -- all dead once the 5 projection GEMMs finish.
  u16* hs_bf  = (u16*)(ws + 0L);         //  8,388,608
  u16* enc_bf = (u16*)(ws + 8388608L);   //  2,097,152
  u16* wq_bf  = (u16*)(ws + 10485760L);  //  2,097,152
  u16* wk_bf  = (u16*)(ws + 12582912L);  //  2,097,152
  u16* wv_bf  = (u16*)(ws + 14680064L);  //  2,097,152 (ends 16,777,216)
  u16* wo_bf  = (u16*)(ws + 16777216L);  //  2,097,152
  u16* wfk_bf = (u16*)(ws + 18874368L);  //  1,048,576
  u16* wfv_bf = (u16*)(ws + 19922944L);  //  1,048,576
  u16* e_bf   = (u16*)(ws + 20971520L);  //    262,144 (2048x64)
  u16* q_bf   = (u16*)(ws + 21233664L);  //  8,388,608 [B,H,S,64]
  u16* k_bf   = (u16*)(ws + 29622272L);  //  8,388,608 [B,H,S,64]
  u16* v_bf   = (u16*)(ws + 38010880L);  //  8,388,608 [B,H,S,64]
  u16* fk_bf  = (u16*)(ws + 46399488L);  //  4,194,304 [B,H,SE,64]
  u16* fv_bf  = (u16*)(ws + 50593792L);  //  4,194,304 [B,H,SE,64]
  u16* ctx_bf = (u16*)(ws + 54788096L);  //  8,388,608 (ends 63,176,704)
  float* ctx1 = (float*)(ws + 0L);       // 16,777,216 f32, aliases dead bufs
  float* y    = (float*)(ws + 0L);       // aliases ctx1 (dead by then)

  k_convert<<<10368, 256, 0, stream>>>(hs, enc, Wq, Wk, Wv, Wo, Wfk, Wfv, de,
                                       hs_bf, enc_bf, wq_bf, wk_bf, wv_bf,
                                       wo_bf, wfk_bf, wfv_bf, e_bf);

  dim3 g4k(8, 32), g2k(8, 16), blk(256);
  k_gemm<0><<<g4k, blk, 0, stream>>>(hs_bf, wq_bf, bq, q_bf, nullptr, 4096,
                                     1024, 1024, 1024, 10);
  k_gemm<0><<<g4k, blk, 0, stream>>>(hs_bf, wk_bf, bk, k_bf, nullptr, 4096,
                                     1024, 1024, 1024, 10);
  k_gemm<0><<<g4k, blk, 0, stream>>>(hs_bf, wv_bf, bv, v_bf, nullptr, 4096,
                                     1024, 1024, 1024, 10);
  k_gemm<0><<<g2k, blk, 0, stream>>>(enc_bf, wfk_bf, bfk, fk_bf, nullptr, 2048,
                                     1024, 512, 512, 9);
  k_gemm<0><<<g2k, blk, 0, stream>>>(enc_bf, wfv_bf, bfv, fv_bf, nullptr, 2048,
                                     1024, 512, 512, 9);

  k_attn_slow_self<<<dim3(4, 64), blk, 0, stream>>>(q_bf, k_bf, v_bf, e_bf,
                                                    mask, ctx1);
  k_attn_slow_enc<<<dim3(4, 64), blk, 0, stream>>>(q_bf, fk_bf, fv_bf, ctx1,
                                                   ctx_bf);

  k_gemm<2><<<g4k, blk, 0, stream>>>(ctx_bf, wo_bf, bo, y, hs, 4096, 1024,
                                     1024, 1024, 10);
  k_ln<<<4096, blk, 0, stream>>>(y, lng, lnb, (float*)d_out);
}

// Round 6
// 2585.152 us; speedup vs baseline: 1.2914x; 1.2914x over previous
//
#include <hip/hip_runtime.h>

// ---------------------------------------------------------------------------
// JonbertaSelfAttention, MI355X gfx950.  BISECTION ROUND 2:
// slow (proven) self-attn + FUSED enc-attn -> isolates the shared fused
// structure (swapped-QK scores, softmax, repack, PV, OMODE=1 V^T) from the
// relative-position bias machinery.
// ---------------------------------------------------------------------------

typedef unsigned short u16;
typedef __attribute__((ext_vector_type(8))) short bf16x8;
typedef __attribute__((ext_vector_type(4))) float f32x4;
typedef __attribute__((ext_vector_type(16))) float f32x16;

#define DEV static __device__ __forceinline__

constexpr int H_ = 16, S_ = 1024;

DEV u16 f2bf(float f) {
  unsigned u = __float_as_uint(f);
  unsigned r = (u + 0x7FFFu + ((u >> 16) & 1u)) >> 16;  // RNE
  return (u16)r;
}
DEV unsigned pack2(float a, float b) {
  return (unsigned)f2bf(a) | ((unsigned)f2bf(b) << 16);
}
DEV float bf2f(u16 u) { return __uint_as_float(((unsigned)u) << 16); }
DEV bf16x8 mk8(unsigned a, unsigned b, unsigned c, unsigned d) {
  union { unsigned u[4]; bf16x8 v; } x;
  x.u[0] = a; x.u[1] = b; x.u[2] = c; x.u[3] = d;
  return x.v;
}
DEV f32x16 zero16() {
  f32x16 z;
#pragma unroll
  for (int i = 0; i < 16; i++) z[i] = 0.f;
  return z;
}
DEV f32x16 mfma32(bf16x8 a, bf16x8 b, f32x16 c) {
  return __builtin_amdgcn_mfma_f32_32x32x16_bf16(a, b, c, 0, 0, 0);
}
DEV f32x4 mfma16(bf16x8 a, bf16x8 b, f32x4 c) {
  return __builtin_amdgcn_mfma_f32_16x16x32_bf16(a, b, c, 0, 0, 0);
}

// ---------------------------------------------------------------------------
// fp32 -> bf16 conversion of all inputs (hardcoded segment table).
// ---------------------------------------------------------------------------
__global__ __launch_bounds__(256) void k_convert(
    const float* __restrict__ hs, const float* __restrict__ enc,
    const float* __restrict__ wq, const float* __restrict__ wk,
    const float* __restrict__ wv, const float* __restrict__ wo,
    const float* __restrict__ wfk, const float* __restrict__ wfv,
    const float* __restrict__ de,
    u16* __restrict__ o_hs, u16* __restrict__ o_enc, u16* __restrict__ o_wq,
    u16* __restrict__ o_wk, u16* __restrict__ o_wv, u16* __restrict__ o_wo,
    u16* __restrict__ o_wfk, u16* __restrict__ o_wfv, u16* __restrict__ o_e) {
  long i = ((long)blockIdx.x * 256 + threadIdx.x) * 4;
  const float* s; u16* d; long base; bool isE = false;
  if (i < 4194304L)        { s = hs;  d = o_hs;  base = 0L; }
  else if (i < 5242880L)   { s = enc; d = o_enc; base = 4194304L; }
  else if (i < 6291456L)   { s = wq;  d = o_wq;  base = 5242880L; }
  else if (i < 7340032L)   { s = wk;  d = o_wk;  base = 6291456L; }
  else if (i < 8388608L)   { s = wv;  d = o_wv;  base = 7340032L; }
  else if (i < 9437184L)   { s = wo;  d = o_wo;  base = 8388608L; }
  else if (i < 9961472L)   { s = wfk; d = o_wfk; base = 9437184L; }
  else if (i < 10485760L)  { s = wfv; d = o_wfv; base = 9961472L; }
  else                     { s = de;  d = o_e;   base = 10485760L; isE = true; }
  long li = i - base;
  uint2 o;
  if (isE && li >= 131008L) {
    o.x = 0u; o.y = 0u;  // zero-pad dist_emb to 2048 rows
  } else {
    float4 v = *(const float4*)(s + li);
    o.x = pack2(v.x, v.y);
    o.y = pack2(v.z, v.w);
  }
  *(uint2*)(d + li) = o;
}

// ---------------------------------------------------------------------------
// bf16 GEMM: C[m,n] = sum_k A[m,k]*W[n,k] + bias[n]  (torch Linear)
// OMODE 0: bf16 out scattered [B,H,Sdim,64]
// OMODE 1: bf16 out scattered [B,H,64,Sdim]
// OMODE 2: f32  out flat [M,N] = acc + bias + resid
// ---------------------------------------------------------------------------
template <int OMODE>
__global__ __launch_bounds__(256) void k_gemm(
    const u16* __restrict__ A, const u16* __restrict__ W,
    const float* __restrict__ bias, void* __restrict__ out,
    const float* __restrict__ resid, int M, int N, int K, int Sdim,
    int sdbits) {
  __shared__ u16 As[128 * 40];
  __shared__ u16 Bs[128 * 40];
  int t = threadIdx.x, w = t >> 6, lane = t & 63;
  int m0 = blockIdx.y * 128, n0 = blockIdx.x * 128;
  int wrow = (w >> 1) * 64, wcol = (w & 1) * 64;
  f32x4 acc[4][4] = {};
  int rs = 32 * w + (lane >> 2);
  int cs = (lane & 3) * 8;
  int nkt = K >> 5;
  for (int kt = 0; kt < nkt; kt++) {
    int k0 = kt << 5;
    bf16x8 ra0 = *(const bf16x8*)(A + (long)(m0 + rs) * K + k0 + cs);
    bf16x8 ra1 = *(const bf16x8*)(A + (long)(m0 + rs + 16) * K + k0 + cs);
    bf16x8 rb0 = *(const bf16x8*)(W + (long)(n0 + rs) * K + k0 + cs);
    bf16x8 rb1 = *(const bf16x8*)(W + (long)(n0 + rs + 16) * K + k0 + cs);
    __syncthreads();
    *(bf16x8*)(As + rs * 40 + cs) = ra0;
    *(bf16x8*)(As + (rs + 16) * 40 + cs) = ra1;
    *(bf16x8*)(Bs + rs * 40 + cs) = rb0;
    *(bf16x8*)(Bs + (rs + 16) * 40 + cs) = rb1;
    __syncthreads();
    bf16x8 af[4], bfr[4];
#pragma unroll
    for (int mi = 0; mi < 4; mi++)
      af[mi] = *(const bf16x8*)(As + (wrow + mi * 16 + (lane & 15)) * 40 +
                                8 * (lane >> 4));
#pragma unroll
    for (int ni = 0; ni < 4; ni++)
      bfr[ni] = *(const bf16x8*)(Bs + (wcol + ni * 16 + (lane & 15)) * 40 +
                                 8 * (lane >> 4));
#pragma unroll
    for (int mi = 0; mi < 4; mi++)
#pragma unroll
      for (int ni = 0; ni < 4; ni++)
        acc[mi][ni] = mfma16(af[mi], bfr[ni], acc[mi][ni]);
  }
#pragma unroll
  for (int mi = 0; mi < 4; mi++) {
#pragma unroll
    for (int ni = 0; ni < 4; ni++) {
      int col = n0 + wcol + ni * 16 + (lane & 15);
      float bcol = bias[col];
#pragma unroll
      for (int e = 0; e < 4; e++) {
        int grow = m0 + wrow + mi * 16 + (lane >> 4) * 4 + e;
        float val = acc[mi][ni][e] + bcol;
        if (OMODE == 2) {
          long idx = (long)grow * N + col;
          ((float*)out)[idx] = val + resid[idx];
        } else {
          int bb = grow >> sdbits, sloc = grow & (Sdim - 1);
          int hh = col >> 6, dd = col & 63;
          long idx;
          if (OMODE == 0)
            idx = ((long)(bb * H_ + hh) * Sdim + sloc) * 64 + dd;
          else
            idx = ((long)(bb * H_ + hh) * 64 + dd) * Sdim + sloc;
          ((u16*)out)[idx] = f2bf(val);
        }
      }
    }
  }
}

// ---------------------------------------------------------------------------
// SLOW self-attention (proven in round 2): one thread per (b,h,query l).
// ---------------------------------------------------------------------------
__global__ __launch_bounds__(256) void k_attn_slow_self(
    const u16* __restrict__ qg, const u16* __restrict__ kg,
    const u16* __restrict__ vg, const u16* __restrict__ eg,
    const float* __restrict__ maskg, float* __restrict__ ctx_f32) {
  int bh = blockIdx.y, bb = bh >> 4, h = bh & 15;
  int l = blockIdx.x * 256 + threadIdx.x;
  const u16* qp = qg + ((long)bh * 1024 + l) * 64;
  float q[64];
#pragma unroll
  for (int d = 0; d < 64; d += 8) {
    bf16x8 v8 = *(const bf16x8*)(qp + d);
#pragma unroll
    for (int j = 0; j < 8; j++) q[d + j] = bf2f((u16)v8[j]);
  }
  const float* mp = maskg + bb * 1024;
  float m = -1e30f, s = 0.f, ctx[64];
#pragma unroll
  for (int d = 0; d < 64; d++) ctx[d] = 0.f;
  for (int r = 0; r < 1024; r++) {
    const u16* kp = kg + ((long)bh * 1024 + r) * 64;
    const u16* ep = eg + (long)(l - r + 1023) * 64;
    float sqk = 0.f, sqe = 0.f, ske = 0.f;
#pragma unroll
    for (int d = 0; d < 64; d += 8) {
      bf16x8 k8 = *(const bf16x8*)(kp + d);
      bf16x8 e8 = *(const bf16x8*)(ep + d);
#pragma unroll
      for (int j = 0; j < 8; j++) {
        float kd = bf2f((u16)k8[j]), ed = bf2f((u16)e8[j]);
        sqk += q[d + j] * kd;
        sqe += q[d + j] * ed;
        ske += kd * ed;
      }
    }
    float sc = (sqk + sqe + ske) * 0.125f + mp[r];
    float mn = fmaxf(m, sc);
    float al = __expf(m - mn), p = __expf(sc - mn);
    m = mn;
    s = s * al + p;
    const u16* vp = vg + ((long)bh * 1024 + r) * 64;
#pragma unroll
    for (int d = 0; d < 64; d += 8) {
      bf16x8 v8 = *(const bf16x8*)(vp + d);
#pragma unroll
      for (int j = 0; j < 8; j++)
        ctx[d + j] = ctx[d + j] * al + p * bf2f((u16)v8[j]);
    }
  }
  float is = 1.f / s;
  long obase = ((long)bb * 1024 + l) * 1024 + h * 64;
#pragma unroll
  for (int d = 0; d < 64; d++) ctx_f32[obase + d] = ctx[d] * is;
}

// ---------------------------------------------------------------------------
// FUSED enc cross-attention (structure test): one wave per 32-row q-tile.
// Swapped scores mfma(K,Q); online softmax; shuffle repack; PV with V^T.
// Adds previously written f32 ctx and emits bf16 ctx for the out-proj.
// ---------------------------------------------------------------------------
template <int NKEYS>
__global__ __launch_bounds__(256) void k_attn_enc(
    const u16* __restrict__ qg, const u16* __restrict__ kg,
    const u16* __restrict__ vTg, const float* __restrict__ ctx_f32,
    u16* __restrict__ ctx_bf) {
  __shared__ float Sb[4][32];
  int t = threadIdx.x, w = t >> 6, lane = t & 63;
  int lo = lane & 31, hh = lane >> 5;
  int bh = blockIdx.y, bb = bh >> 4, h = bh & 15;
  int l0 = blockIdx.x * 128 + w * 32;
  const u16* qp = qg + (long)bh * S_ * 64;
  const u16* kp = kg + (long)bh * NKEYS * 64;
  const u16* vp = vTg + (long)bh * 64 * NKEYS;
  float* Sp = Sb[w];

  bf16x8 qf[4];
#pragma unroll
  for (int kk = 0; kk < 4; kk++)
    qf[kk] = *(const bf16x8*)(qp + (l0 + lo) * 64 + kk * 16 + 8 * hh);

  f32x16 cx0 = zero16(), cx1 = zero16();
  float m_run = -1e30f, s_run = 0.f;
  const float inv = 0.125f;  // 1/sqrt(64)

  for (int r0 = 0; r0 < NKEYS; r0 += 32) {
    bf16x8 kf[4];
#pragma unroll
    for (int kk = 0; kk < 4; kk++)
      kf[kk] = *(const bf16x8*)(kp + (r0 + lo) * 64 + kk * 16 + 8 * hh);
    f32x16 sc = zero16();
#pragma unroll
    for (int kk = 0; kk < 4; kk++) sc = mfma32(kf[kk], qf[kk], sc);

    float pmax = -1e30f;
#pragma unroll
    for (int i = 0; i < 16; i++) {
      float v = sc[i] * inv;
      sc[i] = v;
      pmax = fmaxf(pmax, v);
    }
    pmax = fmaxf(pmax, __shfl_xor(pmax, 32));
    float mnew = fmaxf(m_run, pmax);
    float alpha = __expf(m_run - mnew);
    m_run = mnew;
    float tsum = 0.f;
#pragma unroll
    for (int i = 0; i < 16; i++) {
      float p = __expf(sc[i] - mnew);
      sc[i] = p;
      tsum += p;
    }
    tsum += __shfl_xor(tsum, 32);
    s_run = s_run * alpha + tsum;
    if (hh == 0) Sp[lo] = alpha;
    __builtin_amdgcn_s_waitcnt(0);  // same-wave LDS ordering (paranoia)
#pragma unroll
    for (int i = 0; i < 16; i++) {
      float a = Sp[(i & 3) + 8 * (i >> 2) + 4 * hh];
      cx0[i] *= a;
      cx1[i] *= a;
    }
    // repack P^T (D-layout: key=(i&3)+8*(i>>2)+4*hh, query=lo) -> PV A-frags
    bf16x8 pA[2];
#pragma unroll
    for (int kk = 0; kk < 2; kk++) {
      unsigned a01 = pack2(sc[8 * kk + 0], sc[8 * kk + 1]);
      unsigned a23 = pack2(sc[8 * kk + 2], sc[8 * kk + 3]);
      unsigned b01 = pack2(sc[8 * kk + 4], sc[8 * kk + 5]);
      unsigned b23 = pack2(sc[8 * kk + 6], sc[8 * kk + 7]);
      unsigned c0a = (unsigned)__shfl((int)a01, lo);
      unsigned c0b = (unsigned)__shfl((int)b01, lo);
      unsigned c1a = (unsigned)__shfl((int)a23, lo);
      unsigned c1b = (unsigned)__shfl((int)b23, lo);
      unsigned c2a = (unsigned)__shfl((int)a01, lo + 32);
      unsigned c2b = (unsigned)__shfl((int)b01, lo + 32);
      unsigned c3a = (unsigned)__shfl((int)a23, lo + 32);
      unsigned c3b = (unsigned)__shfl((int)b23, lo + 32);
      pA[kk] = mk8(hh ? c0b : c0a, hh ? c1b : c1a, hh ? c2b : c2a,
                   hh ? c3b : c3a);
    }
#pragma unroll
    for (int nf = 0; nf < 2; nf++) {
#pragma unroll
      for (int kk = 0; kk < 2; kk++) {
        bf16x8 vf = *(const bf16x8*)(vp + (long)(nf * 32 + lo) * NKEYS + r0 +
                                     kk * 16 + 8 * hh);
        if (nf == 0)
          cx0 = mfma32(pA[kk], vf, cx0);
        else
          cx1 = mfma32(pA[kk], vf, cx1);
      }
    }
  }
  if (hh == 0) Sp[lo] = 1.f / s_run;
  __builtin_amdgcn_s_waitcnt(0);
#pragma unroll
  for (int nf = 0; nf < 2; nf++) {
#pragma unroll
    for (int i = 0; i < 16; i++) {
      int rr = (i & 3) + 8 * (i >> 2) + 4 * hh;
      float val = (nf ? cx1[i] : cx0[i]) * Sp[rr];
      long idx = (long)(bb * S_ + l0 + rr) * 1024 + h * 64 + nf * 32 + lo;
      ctx_bf[idx] = f2bf(val + ctx_f32[idx]);
    }
  }
}

// ---------------------------------------------------------------------------
// Row LayerNorm: 1 block per row of y[4096][1024].
// ---------------------------------------------------------------------------
__global__ __launch_bounds__(256) void k_ln(const float* __restrict__ y,
                                            const float* __restrict__ g,
                                            const float* __restrict__ bta,
                                            float* __restrict__ out) {
  int row = blockIdx.x, t = threadIdx.x;
  const float* yr = y + (long)row * 1024;
  float4 v = *(const float4*)(yr + t * 4);
  float s = v.x + v.y + v.z + v.w;
  float q = v.x * v.x + v.y * v.y + v.z * v.z + v.w * v.w;
#pragma unroll
  for (int off = 1; off < 64; off <<= 1) {
    s += __shfl_xor(s, off);
    q += __shfl_xor(q, off);
  }
  __shared__ float ss[4], qq[4];
  if ((t & 63) == 0) {
    ss[t >> 6] = s;
    qq[t >> 6] = q;
  }
  __syncthreads();
  s = ss[0] + ss[1] + ss[2] + ss[3];
  q = qq[0] + qq[1] + qq[2] + qq[3];
  float mu = s * (1.f / 1024.f);
  float var = q * (1.f / 1024.f) - mu * mu;
  float rinv = rsqrtf(var + 1e-12f);
  float4 gv = *(const float4*)(g + t * 4);
  float4 bv = *(const float4*)(bta + t * 4);
  float4 o;
  o.x = (v.x - mu) * rinv * gv.x + bv.x;
  o.y = (v.y - mu) * rinv * gv.y + bv.y;
  o.z = (v.z - mu) * rinv * gv.z + bv.z;
  o.w = (v.w - mu) * rinv * gv.w + bv.w;
  *(float4*)(out + (long)row * 1024 + t * 4) = o;
}

// ---------------------------------------------------------------------------
extern "C" void kernel_launch(void* const* d_in, const int* in_sizes, int n_in,
                              void* d_out, int out_size, void* d_ws,
                              size_t ws_size, hipStream_t stream) {
  (void)in_sizes; (void)n_in; (void)out_size; (void)ws_size;
  const float* hs   = (const float*)d_in[0];
  const float* mask = (const float*)d_in[1];
  const float* enc  = (const float*)d_in[2];
  const float* Wq   = (const float*)d_in[3];
  const float* bq   = (const float*)d_in[4];
  const float* Wk   = (const float*)d_in[5];
  const float* bk   = (const float*)d_in[6];
  const float* Wv   = (const float*)d_in[7];
  const float* bv   = (const float*)d_in[8];
  const float* Wfk  = (const float*)d_in[9];
  const float* bfk  = (const float*)d_in[10];
  const float* Wfv  = (const float*)d_in[11];
  const float* bfv  = (const float*)d_in[12];
  const float* de   = (const float*)d_in[13];
  const float* Wo   = (const float*)d_in[14];
  const float* bo   = (const float*)d_in[15];
  const float* lng  = (const float*)d_in[16];
  const float* lnb  = (const float*)d_in[17];

  char* ws = (char*)d_ws;
  u16* hs_bf  = (u16*)(ws + 0L);
  u16* enc_bf = (u16*)(ws + 8388608L);
  u16* wq_bf  = (u16*)(ws + 10485760L);
  u16* wk_bf  = (u16*)(ws + 12582912L);
  u16* wv_bf  = (u16*)(ws + 14680064L);
  u16* wo_bf  = (u16*)(ws + 16777216L);
  u16* wfk_bf = (u16*)(ws + 18874368L);
  u16* wfv_bf = (u16*)(ws + 19922944L);
  u16* e_bf   = (u16*)(ws + 20971520L);
  u16* q_bf   = (u16*)(ws + 21233664L);  // [B,H,S,64]
  u16* k_bf   = (u16*)(ws + 29622272L);  // [B,H,S,64]
  u16* v_bf   = (u16*)(ws + 38010880L);  // [B,H,S,64]   (slow self)
  u16* fk_bf  = (u16*)(ws + 46399488L);  // [B,H,SE,64]
  u16* fvT_bf = (u16*)(ws + 50593792L);  // [B,H,64,SE]  (fused enc)
  u16* ctx_bf = (u16*)(ws + 54788096L);
  float* ctx1 = (float*)(ws + 0L);
  float* y    = (float*)(ws + 0L);

  k_convert<<<10368, 256, 0, stream>>>(hs, enc, Wq, Wk, Wv, Wo, Wfk, Wfv, de,
                                       hs_bf, enc_bf, wq_bf, wk_bf, wv_bf,
                                       wo_bf, wfk_bf, wfv_bf, e_bf);

  dim3 g4k(8, 32), g2k(8, 16), blk(256);
  k_gemm<0><<<g4k, blk, 0, stream>>>(hs_bf, wq_bf, bq, q_bf, nullptr, 4096,
                                     1024, 1024, 1024, 10);
  k_gemm<0><<<g4k, blk, 0, stream>>>(hs_bf, wk_bf, bk, k_bf, nullptr, 4096,
                                     1024, 1024, 1024, 10);
  k_gemm<0><<<g4k, blk, 0, stream>>>(hs_bf, wv_bf, bv, v_bf, nullptr, 4096,
                                     1024, 1024, 1024, 10);
  k_gemm<0><<<g2k, blk, 0, stream>>>(enc_bf, wfk_bf, bfk, fk_bf, nullptr, 2048,
                                     1024, 512, 512, 9);
  k_gemm<1><<<g2k, blk, 0, stream>>>(enc_bf, wfv_bf, bfv, fvT_bf, nullptr,
                                     2048, 1024, 512, 512, 9);

  k_attn_slow_self<<<dim3(4, 64), blk, 0, stream>>>(q_bf, k_bf, v_bf, e_bf,
                                                    mask, ctx1);
  k_attn_enc<512><<<dim3(8, 64), blk, 0, stream>>>(q_bf, fk_bf, fvT_bf, ctx1,
                                                   ctx_bf);

  k_gemm<2><<<g4k, blk, 0, stream>>>(ctx_bf, wo_bf, bo, y, hs, 4096, 1024,
                                     1024, 1024, 10);
  k_ln<<<4096, blk, 0, stream>>>(y, lng, lnb, (float*)d_out);
}

// Round 7
// 449.043 us; speedup vs baseline: 7.4348x; 5.7570x over previous
//
#include <hip/hip_runtime.h>

// ---------------------------------------------------------------------------
// JonbertaSelfAttention fused pipeline, MI355X gfx950.
// B=4 S=1024 DM=1024 H=16 D=64 SE=512 DF=512 MAXP=1024
// convert(fp32->bf16) -> 5x MFMA GEMM (q,k,vT,fk,fvT)
//   -> fused self-attn w/ band bias (natural-layout LDS, direct band index)
//   -> fused enc-attn (verified round 6) -> out-proj GEMM (+resid) -> LN
// ---------------------------------------------------------------------------

typedef unsigned short u16;
typedef __attribute__((ext_vector_type(8))) short bf16x8;
typedef __attribute__((ext_vector_type(4))) float f32x4;
typedef __attribute__((ext_vector_type(16))) float f32x16;

#define DEV static __device__ __forceinline__

constexpr int H_ = 16, S_ = 1024;

DEV u16 f2bf(float f) {
  unsigned u = __float_as_uint(f);
  unsigned r = (u + 0x7FFFu + ((u >> 16) & 1u)) >> 16;  // RNE
  return (u16)r;
}
DEV unsigned pack2(float a, float b) {
  return (unsigned)f2bf(a) | ((unsigned)f2bf(b) << 16);
}
DEV float bf2f(u16 u) { return __uint_as_float(((unsigned)u) << 16); }
DEV bf16x8 mk8(unsigned a, unsigned b, unsigned c, unsigned d) {
  union { unsigned u[4]; bf16x8 v; } x;
  x.u[0] = a; x.u[1] = b; x.u[2] = c; x.u[3] = d;
  return x.v;
}
DEV f32x16 zero16() {
  f32x16 z;
#pragma unroll
  for (int i = 0; i < 16; i++) z[i] = 0.f;
  return z;
}
DEV f32x16 mfma32(bf16x8 a, bf16x8 b, f32x16 c) {
  return __builtin_amdgcn_mfma_f32_32x32x16_bf16(a, b, c, 0, 0, 0);
}
DEV f32x4 mfma16(bf16x8 a, bf16x8 b, f32x4 c) {
  return __builtin_amdgcn_mfma_f32_16x16x32_bf16(a, b, c, 0, 0, 0);
}

// ---------------------------------------------------------------------------
// fp32 -> bf16 conversion of all inputs (hardcoded segment table).
// ---------------------------------------------------------------------------
__global__ __launch_bounds__(256) void k_convert(
    const float* __restrict__ hs, const float* __restrict__ enc,
    const float* __restrict__ wq, const float* __restrict__ wk,
    const float* __restrict__ wv, const float* __restrict__ wo,
    const float* __restrict__ wfk, const float* __restrict__ wfv,
    const float* __restrict__ de,
    u16* __restrict__ o_hs, u16* __restrict__ o_enc, u16* __restrict__ o_wq,
    u16* __restrict__ o_wk, u16* __restrict__ o_wv, u16* __restrict__ o_wo,
    u16* __restrict__ o_wfk, u16* __restrict__ o_wfv, u16* __restrict__ o_e) {
  long i = ((long)blockIdx.x * 256 + threadIdx.x) * 4;
  const float* s; u16* d; long base; bool isE = false;
  if (i < 4194304L)        { s = hs;  d = o_hs;  base = 0L; }
  else if (i < 5242880L)   { s = enc; d = o_enc; base = 4194304L; }
  else if (i < 6291456L)   { s = wq;  d = o_wq;  base = 5242880L; }
  else if (i < 7340032L)   { s = wk;  d = o_wk;  base = 6291456L; }
  else if (i < 8388608L)   { s = wv;  d = o_wv;  base = 7340032L; }
  else if (i < 9437184L)   { s = wo;  d = o_wo;  base = 8388608L; }
  else if (i < 9961472L)   { s = wfk; d = o_wfk; base = 9437184L; }
  else if (i < 10485760L)  { s = wfv; d = o_wfv; base = 9961472L; }
  else                     { s = de;  d = o_e;   base = 10485760L; isE = true; }
  long li = i - base;
  uint2 o;
  if (isE && li >= 131008L) {
    o.x = 0u; o.y = 0u;  // zero-pad dist_emb to 2048 rows
  } else {
    float4 v = *(const float4*)(s + li);
    o.x = pack2(v.x, v.y);
    o.y = pack2(v.z, v.w);
  }
  *(uint2*)(d + li) = o;
}

// ---------------------------------------------------------------------------
// bf16 GEMM: C[m,n] = sum_k A[m,k]*W[n,k] + bias[n]  (torch Linear)
// OMODE 0: bf16 out scattered [B,H,Sdim,64]
// OMODE 1: bf16 out scattered [B,H,64,Sdim]
// OMODE 2: f32  out flat [M,N] = acc + bias + resid
// ---------------------------------------------------------------------------
template <int OMODE>
__global__ __launch_bounds__(256) void k_gemm(
    const u16* __restrict__ A, const u16* __restrict__ W,
    const float* __restrict__ bias, void* __restrict__ out,
    const float* __restrict__ resid, int M, int N, int K, int Sdim,
    int sdbits) {
  __shared__ u16 As[128 * 40];
  __shared__ u16 Bs[128 * 40];
  int t = threadIdx.x, w = t >> 6, lane = t & 63;
  int m0 = blockIdx.y * 128, n0 = blockIdx.x * 128;
  int wrow = (w >> 1) * 64, wcol = (w & 1) * 64;
  f32x4 acc[4][4] = {};
  int rs = 32 * w + (lane >> 2);
  int cs = (lane & 3) * 8;
  int nkt = K >> 5;
  for (int kt = 0; kt < nkt; kt++) {
    int k0 = kt << 5;
    bf16x8 ra0 = *(const bf16x8*)(A + (long)(m0 + rs) * K + k0 + cs);
    bf16x8 ra1 = *(const bf16x8*)(A + (long)(m0 + rs + 16) * K + k0 + cs);
    bf16x8 rb0 = *(const bf16x8*)(W + (long)(n0 + rs) * K + k0 + cs);
    bf16x8 rb1 = *(const bf16x8*)(W + (long)(n0 + rs + 16) * K + k0 + cs);
    __syncthreads();
    *(bf16x8*)(As + rs * 40 + cs) = ra0;
    *(bf16x8*)(As + (rs + 16) * 40 + cs) = ra1;
    *(bf16x8*)(Bs + rs * 40 + cs) = rb0;
    *(bf16x8*)(Bs + (rs + 16) * 40 + cs) = rb1;
    __syncthreads();
    bf16x8 af[4], bfr[4];
#pragma unroll
    for (int mi = 0; mi < 4; mi++)
      af[mi] = *(const bf16x8*)(As + (wrow + mi * 16 + (lane & 15)) * 40 +
                                8 * (lane >> 4));
#pragma unroll
    for (int ni = 0; ni < 4; ni++)
      bfr[ni] = *(const bf16x8*)(Bs + (wcol + ni * 16 + (lane & 15)) * 40 +
                                 8 * (lane >> 4));
#pragma unroll
    for (int mi = 0; mi < 4; mi++)
#pragma unroll
      for (int ni = 0; ni < 4; ni++)
        acc[mi][ni] = mfma16(af[mi], bfr[ni], acc[mi][ni]);
  }
#pragma unroll
  for (int mi = 0; mi < 4; mi++) {
#pragma unroll
    for (int ni = 0; ni < 4; ni++) {
      int col = n0 + wcol + ni * 16 + (lane & 15);
      float bcol = bias[col];
#pragma unroll
      for (int e = 0; e < 4; e++) {
        int grow = m0 + wrow + mi * 16 + (lane >> 4) * 4 + e;
        float val = acc[mi][ni][e] + bcol;
        if (OMODE == 2) {
          long idx = (long)grow * N + col;
          ((float*)out)[idx] = val + resid[idx];
        } else {
          int bb = grow >> sdbits, sloc = grow & (Sdim - 1);
          int hh = col >> 6, dd = col & 63;
          long idx;
          if (OMODE == 0)
            idx = ((long)(bb * H_ + hh) * Sdim + sloc) * 64 + dd;
          else
            idx = ((long)(bb * H_ + hh) * 64 + dd) * Sdim + sloc;
          ((u16*)out)[idx] = f2bf(val);
        }
      }
    }
  }
}

// ---------------------------------------------------------------------------
// FUSED self-attention with relative-position band bias.
// One wave per 32-row q-tile. Structure identical to the verified enc kernel;
// bias via banded 32x32 MFMAs stored in NATURAL layout:
//   Ub[dl][j] = q[l0+dl].E[mbase+j],  Vb[dr][j] = k[r0+dr].E[mbase+j]
// read with direct band index j = 31+lo-rr (always in [0,62]).
// Writes f32 ctx.
// ---------------------------------------------------------------------------
template <int NKEYS>
__global__ __launch_bounds__(256) void k_attn_self(
    const u16* __restrict__ qg, const u16* __restrict__ kg,
    const u16* __restrict__ vTg, const u16* __restrict__ eg,
    const float* __restrict__ maskg, float* __restrict__ ctx_f32) {
  __shared__ u16 Ub[4][32 * 64];
  __shared__ u16 Vb[4][32 * 64];
  __shared__ float Sb[4][32];
  int t = threadIdx.x, w = t >> 6, lane = t & 63;
  int lo = lane & 31, hh = lane >> 5;
  int bh = blockIdx.y, bb = bh >> 4, h = bh & 15;
  int l0 = blockIdx.x * 128 + w * 32;
  const u16* qp = qg + (long)bh * S_ * 64;
  const u16* kp = kg + (long)bh * NKEYS * 64;
  const u16* vp = vTg + (long)bh * 64 * NKEYS;
  const float* mp = maskg + bb * S_;
  u16* Up = Ub[w];
  u16* Vp = Vb[w];
  float* Sp = Sb[w];

  bf16x8 qf[4];
#pragma unroll
  for (int kk = 0; kk < 4; kk++)
    qf[kk] = *(const bf16x8*)(qp + (l0 + lo) * 64 + kk * 16 + 8 * hh);

  f32x16 cx0 = zero16(), cx1 = zero16();
  float m_run = -1e30f, s_run = 0.f;
  const float inv = 0.125f;  // 1/sqrt(64)

  for (int r0 = 0; r0 < NKEYS; r0 += 32) {
    bf16x8 kf[4];
#pragma unroll
    for (int kk = 0; kk < 4; kk++)
      kf[kk] = *(const bf16x8*)(kp + (r0 + lo) * 64 + kk * 16 + 8 * hh);
    f32x16 sc = zero16();
#pragma unroll
    for (int kk = 0; kk < 4; kk++) sc = mfma32(kf[kk], qf[kk], sc);

    // --- band bias: E rows mbase..mbase+63 cover distances of this tile ---
    int mbase = l0 - r0 + 992;  // (l0+dl)-(r0+dr)+1023 = mbase + (31+dl-dr)
#pragma unroll
    for (int nf = 0; nf < 2; nf++) {
      bf16x8 ef[4];
#pragma unroll
      for (int kk = 0; kk < 4; kk++)
        ef[kk] = *(const bf16x8*)(eg + (long)(mbase + nf * 32 + lo) * 64 +
                                  kk * 16 + 8 * hh);
      f32x16 uu = zero16(), vv = zero16();
#pragma unroll
      for (int kk = 0; kk < 4; kk++) uu = mfma32(qf[kk], ef[kk], uu);
#pragma unroll
      for (int kk = 0; kk < 4; kk++) vv = mfma32(kf[kk], ef[kk], vv);
      int j = nf * 32 + lo;
#pragma unroll
      for (int i = 0; i < 16; i++) {
        int dl = (i & 3) + 8 * (i >> 2) + 4 * hh;  // D-row
        Up[dl * 64 + j] = f2bf(uu[i]);
        Vp[dl * 64 + j] = f2bf(vv[i]);
      }
    }
    __builtin_amdgcn_s_waitcnt(0);  // LDS stores visible before reads

    float pmax = -1e30f;
#pragma unroll
    for (int i = 0; i < 16; i++) {
      int rr = (i & 3) + 8 * (i >> 2) + 4 * hh;  // key index r_loc
      int jb = 31 + lo - rr;                     // band index in [0,62]
      float ubv = bf2f(Up[lo * 64 + jb]);
      float vbv = bf2f(Vp[rr * 64 + jb]);
      float v = (sc[i] + ubv + vbv) * inv + mp[r0 + rr];
      sc[i] = v;
      pmax = fmaxf(pmax, v);
    }
    pmax = fmaxf(pmax, __shfl_xor(pmax, 32));
    float mnew = fmaxf(m_run, pmax);
    float alpha = __expf(m_run - mnew);
    m_run = mnew;
    float tsum = 0.f;
#pragma unroll
    for (int i = 0; i < 16; i++) {
      float p = __expf(sc[i] - mnew);
      sc[i] = p;
      tsum += p;
    }
    tsum += __shfl_xor(tsum, 32);
    s_run = s_run * alpha + tsum;
    if (hh == 0) Sp[lo] = alpha;
    __builtin_amdgcn_s_waitcnt(0);
#pragma unroll
    for (int i = 0; i < 16; i++) {
      float a = Sp[(i & 3) + 8 * (i >> 2) + 4 * hh];
      cx0[i] *= a;
      cx1[i] *= a;
    }
    // repack P^T (D-layout: key=(i&3)+8*(i>>2)+4*hh, query=lo) -> PV A-frags
    bf16x8 pA[2];
#pragma unroll
    for (int kk = 0; kk < 2; kk++) {
      unsigned a01 = pack2(sc[8 * kk + 0], sc[8 * kk + 1]);
      unsigned a23 = pack2(sc[8 * kk + 2], sc[8 * kk + 3]);
      unsigned b01 = pack2(sc[8 * kk + 4], sc[8 * kk + 5]);
      unsigned b23 = pack2(sc[8 * kk + 6], sc[8 * kk + 7]);
      unsigned c0a = (unsigned)__shfl((int)a01, lo);
      unsigned c0b = (unsigned)__shfl((int)b01, lo);
      unsigned c1a = (unsigned)__shfl((int)a23, lo);
      unsigned c1b = (unsigned)__shfl((int)b23, lo);
      unsigned c2a = (unsigned)__shfl((int)a01, lo + 32);
      unsigned c2b = (unsigned)__shfl((int)b01, lo + 32);
      unsigned c3a = (unsigned)__shfl((int)a23, lo + 32);
      unsigned c3b = (unsigned)__shfl((int)b23, lo + 32);
      pA[kk] = mk8(hh ? c0b : c0a, hh ? c1b : c1a, hh ? c2b : c2a,
                   hh ? c3b : c3a);
    }
#pragma unroll
    for (int nf = 0; nf < 2; nf++) {
#pragma unroll
      for (int kk = 0; kk < 2; kk++) {
        bf16x8 vf = *(const bf16x8*)(vp + (long)(nf * 32 + lo) * NKEYS + r0 +
                                     kk * 16 + 8 * hh);
        if (nf == 0)
          cx0 = mfma32(pA[kk], vf, cx0);
        else
          cx1 = mfma32(pA[kk], vf, cx1);
      }
    }
  }
  if (hh == 0) Sp[lo] = 1.f / s_run;
  __builtin_amdgcn_s_waitcnt(0);
#pragma unroll
  for (int nf = 0; nf < 2; nf++) {
#pragma unroll
    for (int i = 0; i < 16; i++) {
      int rr = (i & 3) + 8 * (i >> 2) + 4 * hh;
      float val = (nf ? cx1[i] : cx0[i]) * Sp[rr];
      long idx = (long)(bb * S_ + l0 + rr) * 1024 + h * 64 + nf * 32 + lo;
      ctx_f32[idx] = val;
    }
  }
}

// ---------------------------------------------------------------------------
// FUSED enc cross-attention (verified round 6, verbatim).
// ---------------------------------------------------------------------------
template <int NKEYS>
__global__ __launch_bounds__(256) void k_attn_enc(
    const u16* __restrict__ qg, const u16* __restrict__ kg,
    const u16* __restrict__ vTg, const float* __restrict__ ctx_f32,
    u16* __restrict__ ctx_bf) {
  __shared__ float Sb[4][32];
  int t = threadIdx.x, w = t >> 6, lane = t & 63;
  int lo = lane & 31, hh = lane >> 5;
  int bh = blockIdx.y, bb = bh >> 4, h = bh & 15;
  int l0 = blockIdx.x * 128 + w * 32;
  const u16* qp = qg + (long)bh * S_ * 64;
  const u16* kp = kg + (long)bh * NKEYS * 64;
  const u16* vp = vTg + (long)bh * 64 * NKEYS;
  float* Sp = Sb[w];

  bf16x8 qf[4];
#pragma unroll
  for (int kk = 0; kk < 4; kk++)
    qf[kk] = *(const bf16x8*)(qp + (l0 + lo) * 64 + kk * 16 + 8 * hh);

  f32x16 cx0 = zero16(), cx1 = zero16();
  float m_run = -1e30f, s_run = 0.f;
  const float inv = 0.125f;  // 1/sqrt(64)

  for (int r0 = 0; r0 < NKEYS; r0 += 32) {
    bf16x8 kf[4];
#pragma unroll
    for (int kk = 0; kk < 4; kk++)
      kf[kk] = *(const bf16x8*)(kp + (r0 + lo) * 64 + kk * 16 + 8 * hh);
    f32x16 sc = zero16();
#pragma unroll
    for (int kk = 0; kk < 4; kk++) sc = mfma32(kf[kk], qf[kk], sc);

    float pmax = -1e30f;
#pragma unroll
    for (int i = 0; i < 16; i++) {
      float v = sc[i] * inv;
      sc[i] = v;
      pmax = fmaxf(pmax, v);
    }
    pmax = fmaxf(pmax, __shfl_xor(pmax, 32));
    float mnew = fmaxf(m_run, pmax);
    float alpha = __expf(m_run - mnew);
    m_run = mnew;
    float tsum = 0.f;
#pragma unroll
    for (int i = 0; i < 16; i++) {
      float p = __expf(sc[i] - mnew);
      sc[i] = p;
      tsum += p;
    }
    tsum += __shfl_xor(tsum, 32);
    s_run = s_run * alpha + tsum;
    if (hh == 0) Sp[lo] = alpha;
    __builtin_amdgcn_s_waitcnt(0);
#pragma unroll
    for (int i = 0; i < 16; i++) {
      float a = Sp[(i & 3) + 8 * (i >> 2) + 4 * hh];
      cx0[i] *= a;
      cx1[i] *= a;
    }
    bf16x8 pA[2];
#pragma unroll
    for (int kk = 0; kk < 2; kk++) {
      unsigned a01 = pack2(sc[8 * kk + 0], sc[8 * kk + 1]);
      unsigned a23 = pack2(sc[8 * kk + 2], sc[8 * kk + 3]);
      unsigned b01 = pack2(sc[8 * kk + 4], sc[8 * kk + 5]);
      unsigned b23 = pack2(sc[8 * kk + 6], sc[8 * kk + 7]);
      unsigned c0a = (unsigned)__shfl((int)a01, lo);
      unsigned c0b = (unsigned)__shfl((int)b01, lo);
      unsigned c1a = (unsigned)__shfl((int)a23, lo);
      unsigned c1b = (unsigned)__shfl((int)b23, lo);
      unsigned c2a = (unsigned)__shfl((int)a01, lo + 32);
      unsigned c2b = (unsigned)__shfl((int)b01, lo + 32);
      unsigned c3a = (unsigned)__shfl((int)a23, lo + 32);
      unsigned c3b = (unsigned)__shfl((int)b23, lo + 32);
      pA[kk] = mk8(hh ? c0b : c0a, hh ? c1b : c1a, hh ? c2b : c2a,
                   hh ? c3b : c3a);
    }
#pragma unroll
    for (int nf = 0; nf < 2; nf++) {
#pragma unroll
      for (int kk = 0; kk < 2; kk++) {
        bf16x8 vf = *(const bf16x8*)(vp + (long)(nf * 32 + lo) * NKEYS + r0 +
                                     kk * 16 + 8 * hh);
        if (nf == 0)
          cx0 = mfma32(pA[kk], vf, cx0);
        else
          cx1 = mfma32(pA[kk], vf, cx1);
      }
    }
  }
  if (hh == 0) Sp[lo] = 1.f / s_run;
  __builtin_amdgcn_s_waitcnt(0);
#pragma unroll
  for (int nf = 0; nf < 2; nf++) {
#pragma unroll
    for (int i = 0; i < 16; i++) {
      int rr = (i & 3) + 8 * (i >> 2) + 4 * hh;
      float val = (nf ? cx1[i] : cx0[i]) * Sp[rr];
      long idx = (long)(bb * S_ + l0 + rr) * 1024 + h * 64 + nf * 32 + lo;
      ctx_bf[idx] = f2bf(val + ctx_f32[idx]);
    }
  }
}

// ---------------------------------------------------------------------------
// Row LayerNorm: 1 block per row of y[4096][1024].
// ---------------------------------------------------------------------------
__global__ __launch_bounds__(256) void k_ln(const float* __restrict__ y,
                                            const float* __restrict__ g,
                                            const float* __restrict__ bta,
                                            float* __restrict__ out) {
  int row = blockIdx.x, t = threadIdx.x;
  const float* yr = y + (long)row * 1024;
  float4 v = *(const float4*)(yr + t * 4);
  float s = v.x + v.y + v.z + v.w;
  float q = v.x * v.x + v.y * v.y + v.z * v.z + v.w * v.w;
#pragma unroll
  for (int off = 1; off < 64; off <<= 1) {
    s += __shfl_xor(s, off);
    q += __shfl_xor(q, off);
  }
  __shared__ float ss[4], qq[4];
  if ((t & 63) == 0) {
    ss[t >> 6] = s;
    qq[t >> 6] = q;
  }
  __syncthreads();
  s = ss[0] + ss[1] + ss[2] + ss[3];
  q = qq[0] + qq[1] + qq[2] + qq[3];
  float mu = s * (1.f / 1024.f);
  float var = q * (1.f / 1024.f) - mu * mu;
  float rinv = rsqrtf(var + 1e-12f);
  float4 gv = *(const float4*)(g + t * 4);
  float4 bv = *(const float4*)(bta + t * 4);
  float4 o;
  o.x = (v.x - mu) * rinv * gv.x + bv.x;
  o.y = (v.y - mu) * rinv * gv.y + bv.y;
  o.z = (v.z - mu) * rinv * gv.z + bv.z;
  o.w = (v.w - mu) * rinv * gv.w + bv.w;
  *(float4*)(out + (long)row * 1024 + t * 4) = o;
}

// ---------------------------------------------------------------------------
extern "C" void kernel_launch(void* const* d_in, const int* in_sizes, int n_in,
                              void* d_out, int out_size, void* d_ws,
                              size_t ws_size, hipStream_t stream) {
  (void)in_sizes; (void)n_in; (void)out_size; (void)ws_size;
  const float* hs   = (const float*)d_in[0];
  const float* mask = (const float*)d_in[1];
  const float* enc  = (const float*)d_in[2];
  const float* Wq   = (const float*)d_in[3];
  const float* bq   = (const float*)d_in[4];
  const float* Wk   = (const float*)d_in[5];
  const float* bk   = (const float*)d_in[6];
  const float* Wv   = (const float*)d_in[7];
  const float* bv   = (const float*)d_in[8];
  const float* Wfk  = (const float*)d_in[9];
  const float* bfk  = (const float*)d_in[10];
  const float* Wfv  = (const float*)d_in[11];
  const float* bfv  = (const float*)d_in[12];
  const float* de   = (const float*)d_in[13];
  const float* Wo   = (const float*)d_in[14];
  const float* bo   = (const float*)d_in[15];
  const float* lng  = (const float*)d_in[16];
  const float* lnb  = (const float*)d_in[17];

  char* ws = (char*)d_ws;
  // Compact layout (63.2 MB). ctx1/y alias the first 16 MB (dead after GEMMs).
  u16* hs_bf  = (u16*)(ws + 0L);
  u16* enc_bf = (u16*)(ws + 8388608L);
  u16* wq_bf  = (u16*)(ws + 10485760L);
  u16* wk_bf  = (u16*)(ws + 12582912L);
  u16* wv_bf  = (u16*)(ws + 14680064L);
  u16* wo_bf  = (u16*)(ws + 16777216L);
  u16* wfk_bf = (u16*)(ws + 18874368L);
  u16* wfv_bf = (u16*)(ws + 19922944L);
  u16* e_bf   = (u16*)(ws + 20971520L);  // 2048x64 (row 2047 zeroed)
  u16* q_bf   = (u16*)(ws + 21233664L);  // [B,H,S,64]
  u16* k_bf   = (u16*)(ws + 29622272L);  // [B,H,S,64]
  u16* vT_bf  = (u16*)(ws + 38010880L);  // [B,H,64,S]
  u16* fk_bf  = (u16*)(ws + 46399488L);  // [B,H,SE,64]
  u16* fvT_bf = (u16*)(ws + 50593792L);  // [B,H,64,SE]
  u16* ctx_bf = (u16*)(ws + 54788096L);
  float* ctx1 = (float*)(ws + 0L);
  float* y    = (float*)(ws + 0L);

  k_convert<<<10368, 256, 0, stream>>>(hs, enc, Wq, Wk, Wv, Wo, Wfk, Wfv, de,
                                       hs_bf, enc_bf, wq_bf, wk_bf, wv_bf,
                                       wo_bf, wfk_bf, wfv_bf, e_bf);

  dim3 g4k(8, 32), g2k(8, 16), blk(256);
  k_gemm<0><<<g4k, blk, 0, stream>>>(hs_bf, wq_bf, bq, q_bf, nullptr, 4096,
                                     1024, 1024, 1024, 10);
  k_gemm<0><<<g4k, blk, 0, stream>>>(hs_bf, wk_bf, bk, k_bf, nullptr, 4096,
                                     1024, 1024, 1024, 10);
  k_gemm<1><<<g4k, blk, 0, stream>>>(hs_bf, wv_bf, bv, vT_bf, nullptr, 4096,
                                     1024, 1024, 1024, 10);
  k_gemm<0><<<g2k, blk, 0, stream>>>(enc_bf, wfk_bf, bfk, fk_bf, nullptr, 2048,
                                     1024, 512, 512, 9);
  k_gemm<1><<<g2k, blk, 0, stream>>>(enc_bf, wfv_bf, bfv, fvT_bf, nullptr,
                                     2048, 1024, 512, 512, 9);

  k_attn_self<1024><<<dim3(8, 64), blk, 0, stream>>>(q_bf, k_bf, vT_bf, e_bf,
                                                     mask, ctx1);
  k_attn_enc<512><<<dim3(8, 64), blk, 0, stream>>>(q_bf, fk_bf, fvT_bf, ctx1,
                                                   ctx_bf);

  k_gemm<2><<<g4k, blk, 0, stream>>>(ctx_bf, wo_bf, bo, y, hs, 4096, 1024,
                                     1024, 1024, 10);
  k_ln<<<4096, blk, 0, stream>>>(y, lng, lnb, (float*)d_out);
}

// Round 8
// 418.737 us; speedup vs baseline: 7.9729x; 1.0724x over previous
//
#include <hip/hip_runtime.h>

// ---------------------------------------------------------------------------
// JonbertaSelfAttention fused pipeline, MI355X gfx950.
// convert -> QKV GEMM (fused, glds) -> FKV GEMM (fused) ->
// self-attn (K-split x2, band bias) -> enc-attn (+self merge, ->bf16) ->
// out-proj GEMM (+resid) -> LN
// ---------------------------------------------------------------------------

typedef unsigned short u16;
typedef __attribute__((ext_vector_type(8))) short bf16x8;
typedef __attribute__((ext_vector_type(4))) float f32x4;
typedef __attribute__((ext_vector_type(16))) float f32x16;

#define DEV static __device__ __forceinline__

constexpr int H_ = 16, S_ = 1024;

DEV u16 f2bf(float f) {
  unsigned u = __float_as_uint(f);
  unsigned r = (u + 0x7FFFu + ((u >> 16) & 1u)) >> 16;  // RNE
  return (u16)r;
}
DEV unsigned pack2(float a, float b) {
  return (unsigned)f2bf(a) | ((unsigned)f2bf(b) << 16);
}
DEV float bf2f(u16 u) { return __uint_as_float(((unsigned)u) << 16); }
DEV bf16x8 mk8(unsigned a, unsigned b, unsigned c, unsigned d) {
  union { unsigned u[4]; bf16x8 v; } x;
  x.u[0] = a; x.u[1] = b; x.u[2] = c; x.u[3] = d;
  return x.v;
}
DEV f32x16 zero16() {
  f32x16 z;
#pragma unroll
  for (int i = 0; i < 16; i++) z[i] = 0.f;
  return z;
}
DEV f32x16 mfma32(bf16x8 a, bf16x8 b, f32x16 c) {
  return __builtin_amdgcn_mfma_f32_32x32x16_bf16(a, b, c, 0, 0, 0);
}
DEV f32x4 mfma16(bf16x8 a, bf16x8 b, f32x4 c) {
  return __builtin_amdgcn_mfma_f32_16x16x32_bf16(a, b, c, 0, 0, 0);
}
DEV void gl_lds(const u16* g, u16* l) {  // 16B per lane, dest wave-uniform
  __builtin_amdgcn_global_load_lds(
      (const __attribute__((address_space(1))) unsigned int*)g,
      (__attribute__((address_space(3))) unsigned int*)l, 16, 0, 0);
}
#define LGKM_FENCE()                                   \
  asm volatile("s_waitcnt lgkmcnt(0)" ::: "memory");   \
  __builtin_amdgcn_sched_barrier(0)

// ---------------------------------------------------------------------------
// fp32 -> bf16 conversion of all inputs (hardcoded segment table).
// ---------------------------------------------------------------------------
__global__ __launch_bounds__(256) void k_convert(
    const float* __restrict__ hs, const float* __restrict__ enc,
    const float* __restrict__ wq, const float* __restrict__ wk,
    const float* __restrict__ wv, const float* __restrict__ wo,
    const float* __restrict__ wfk, const float* __restrict__ wfv,
    const float* __restrict__ de,
    u16* __restrict__ o_hs, u16* __restrict__ o_enc, u16* __restrict__ o_wq,
    u16* __restrict__ o_wk, u16* __restrict__ o_wv, u16* __restrict__ o_wo,
    u16* __restrict__ o_wfk, u16* __restrict__ o_wfv, u16* __restrict__ o_e) {
  long i = ((long)blockIdx.x * 256 + threadIdx.x) * 4;
  const float* s; u16* d; long base; bool isE = false;
  if (i < 4194304L)        { s = hs;  d = o_hs;  base = 0L; }
  else if (i < 5242880L)   { s = enc; d = o_enc; base = 4194304L; }
  else if (i < 6291456L)   { s = wq;  d = o_wq;  base = 5242880L; }
  else if (i < 7340032L)   { s = wk;  d = o_wk;  base = 6291456L; }
  else if (i < 8388608L)   { s = wv;  d = o_wv;  base = 7340032L; }
  else if (i < 9437184L)   { s = wo;  d = o_wo;  base = 8388608L; }
  else if (i < 9961472L)   { s = wfk; d = o_wfk; base = 9437184L; }
  else if (i < 10485760L)  { s = wfv; d = o_wfv; base = 9961472L; }
  else                     { s = de;  d = o_e;   base = 10485760L; isE = true; }
  long li = i - base;
  uint2 o;
  if (isE && li >= 131008L) {
    o.x = 0u; o.y = 0u;  // zero-pad dist_emb to 2048 rows
  } else {
    float4 v = *(const float4*)(s + li);
    o.x = pack2(v.x, v.y);
    o.y = pack2(v.z, v.w);
  }
  *(uint2*)(d + li) = o;
}

// ---------------------------------------------------------------------------
// Fused projection GEMM: C[m,n] = A[m,:].W[n,:] + bias, 64x128 tile, BK=32,
// global_load_lds staging, 4 waves (32x64 out each). N spans stacked
// projections; proj = n0>>10 is block-uniform. Scatter to [B,H,Sdim,64]
// (or transposed [B,H,64,Sdim] when proj==vproj).
// ---------------------------------------------------------------------------
__global__ __launch_bounds__(256) void k_gemm_proj(
    const u16* __restrict__ A, const u16* __restrict__ W,
    const float* __restrict__ b0, const float* __restrict__ b1,
    const float* __restrict__ b2, u16* __restrict__ d0, u16* __restrict__ d1,
    u16* __restrict__ d2, int K, int Sdim, int sdbits, int vproj) {
  __shared__ u16 As[64 * 32];
  __shared__ u16 Bs[128 * 32];
  int t = threadIdx.x, w = t >> 6, lane = t & 63;
  int m0 = blockIdx.y * 64, n0 = blockIdx.x * 128;
  int wrow = (w >> 1) * 32, wcol = (w & 1) * 64;
  f32x4 acc[2][4] = {};
  int srow = lane >> 2;            // 0..15 within a 16-row issue
  int scol = (lane & 3) * 8;       // staging col (elems)
  int nkt = K >> 5;
  for (int kt = 0; kt < nkt; kt++) {
    int k0 = kt << 5;
    __syncthreads();  // prior iter's ds_reads done before overwrite
    gl_lds(A + (long)(m0 + 16 * w + srow) * K + k0 + scol, As + w * 512);
    gl_lds(W + (long)(n0 + 32 * w + srow) * K + k0 + scol, Bs + w * 1024);
    gl_lds(W + (long)(n0 + 32 * w + 16 + srow) * K + k0 + scol,
           Bs + w * 1024 + 512);
    asm volatile("s_waitcnt vmcnt(0)" ::: "memory");
    __syncthreads();
    bf16x8 af[2], bfr[4];
#pragma unroll
    for (int mi = 0; mi < 2; mi++)
      af[mi] = *(const bf16x8*)(As + (wrow + mi * 16 + (lane & 15)) * 32 +
                                8 * (lane >> 4));
#pragma unroll
    for (int ni = 0; ni < 4; ni++)
      bfr[ni] = *(const bf16x8*)(Bs + (wcol + ni * 16 + (lane & 15)) * 32 +
                                 8 * (lane >> 4));
#pragma unroll
    for (int mi = 0; mi < 2; mi++)
#pragma unroll
      for (int ni = 0; ni < 4; ni++)
        acc[mi][ni] = mfma16(af[mi], bfr[ni], acc[mi][ni]);
  }
  int proj = n0 >> 10;  // block-uniform (128 | 1024)
  const float* bp = proj == 0 ? b0 : (proj == 1 ? b1 : b2);
  u16* dp = proj == 0 ? d0 : (proj == 1 ? d1 : d2);
  bool tr = (proj == vproj);
#pragma unroll
  for (int ni = 0; ni < 4; ni++) {
    int col = n0 + wcol + ni * 16 + (lane & 15);
    int cq = col & 1023;
    float bcol = bp[cq];
    int hh = cq >> 6, dd = cq & 63;
#pragma unroll
    for (int mi = 0; mi < 2; mi++) {
#pragma unroll
      for (int e = 0; e < 4; e++) {
        int grow = m0 + wrow + mi * 16 + (lane >> 4) * 4 + e;
        int bb = grow >> sdbits, sloc = grow & (Sdim - 1);
        long idx = tr ? ((long)(bb * H_ + hh) * 64 + dd) * Sdim + sloc
                      : ((long)(bb * H_ + hh) * Sdim + sloc) * 64 + dd;
        dp[idx] = f2bf(acc[mi][ni][e] + bcol);
      }
    }
  }
}

// ---------------------------------------------------------------------------
// Out-proj GEMM: f32 out[m][n] = A.Wo + bo + resid. Same 64x128 glds core.
// ---------------------------------------------------------------------------
__global__ __launch_bounds__(256) void k_gemm_out(
    const u16* __restrict__ A, const u16* __restrict__ W,
    const float* __restrict__ bias, float* __restrict__ out,
    const float* __restrict__ resid, int K) {
  __shared__ u16 As[64 * 32];
  __shared__ u16 Bs[128 * 32];
  int t = threadIdx.x, w = t >> 6, lane = t & 63;
  int m0 = blockIdx.y * 64, n0 = blockIdx.x * 128;
  int wrow = (w >> 1) * 32, wcol = (w & 1) * 64;
  f32x4 acc[2][4] = {};
  int srow = lane >> 2;
  int scol = (lane & 3) * 8;
  int nkt = K >> 5;
  for (int kt = 0; kt < nkt; kt++) {
    int k0 = kt << 5;
    __syncthreads();
    gl_lds(A + (long)(m0 + 16 * w + srow) * K + k0 + scol, As + w * 512);
    gl_lds(W + (long)(n0 + 32 * w + srow) * K + k0 + scol, Bs + w * 1024);
    gl_lds(W + (long)(n0 + 32 * w + 16 + srow) * K + k0 + scol,
           Bs + w * 1024 + 512);
    asm volatile("s_waitcnt vmcnt(0)" ::: "memory");
    __syncthreads();
    bf16x8 af[2], bfr[4];
#pragma unroll
    for (int mi = 0; mi < 2; mi++)
      af[mi] = *(const bf16x8*)(As + (wrow + mi * 16 + (lane & 15)) * 32 +
                                8 * (lane >> 4));
#pragma unroll
    for (int ni = 0; ni < 4; ni++)
      bfr[ni] = *(const bf16x8*)(Bs + (wcol + ni * 16 + (lane & 15)) * 32 +
                                 8 * (lane >> 4));
#pragma unroll
    for (int mi = 0; mi < 2; mi++)
#pragma unroll
      for (int ni = 0; ni < 4; ni++)
        acc[mi][ni] = mfma16(af[mi], bfr[ni], acc[mi][ni]);
  }
#pragma unroll
  for (int ni = 0; ni < 4; ni++) {
    int col = n0 + wcol + ni * 16 + (lane & 15);
    float bcol = bias[col];
#pragma unroll
    for (int mi = 0; mi < 2; mi++) {
#pragma unroll
      for (int e = 0; e < 4; e++) {
        int grow = m0 + wrow + mi * 16 + (lane >> 4) * 4 + e;
        long idx = (long)grow * 1024 + col;
        out[idx] = acc[mi][ni][e] + bcol + resid[idx];
      }
    }
  }
}

// ---------------------------------------------------------------------------
// Self-attention, K-split x2 (blockIdx.z). Band bias via natural-layout LDS
// (verified round 7). Writes bf16 numerator P_z + per-query (m,s).
// ---------------------------------------------------------------------------
__global__ __launch_bounds__(256) void k_attn_self(
    const u16* __restrict__ qg, const u16* __restrict__ kg,
    const u16* __restrict__ vTg, const u16* __restrict__ eg,
    const float* __restrict__ maskg, u16* __restrict__ P0,
    u16* __restrict__ P1, float2* __restrict__ ms0,
    float2* __restrict__ ms1) {
  __shared__ u16 Ub[4][32 * 64];
  __shared__ u16 Vb[4][32 * 64];
  __shared__ float Sb[4][32];
  int t = threadIdx.x, w = t >> 6, lane = t & 63;
  int lo = lane & 31, hh = lane >> 5;
  int bh = blockIdx.y;
  int z = blockIdx.z;
  int kb = z << 9;
  u16* Pp = z ? P1 : P0;
  float2* msp = z ? ms1 : ms0;
  int l0 = blockIdx.x * 128 + w * 32;
  const u16* qp = qg + (long)bh * S_ * 64;
  const u16* kp = kg + (long)bh * S_ * 64;
  const u16* vp = vTg + (long)bh * 64 * S_;
  const float* mp = maskg + (bh >> 4) * S_;
  u16* Up = Ub[w];
  u16* Vp = Vb[w];
  float* Sp = Sb[w];

  bf16x8 qf[4];
#pragma unroll
  for (int kk = 0; kk < 4; kk++)
    qf[kk] = *(const bf16x8*)(qp + (l0 + lo) * 64 + kk * 16 + 8 * hh);

  f32x16 cx0 = zero16(), cx1 = zero16();
  float m_run = -1e30f, s_run = 0.f;
  const float inv = 0.125f;  // 1/sqrt(64)

  for (int r0 = kb; r0 < kb + 512; r0 += 32) {
    bf16x8 kf[4];
#pragma unroll
    for (int kk = 0; kk < 4; kk++)
      kf[kk] = *(const bf16x8*)(kp + (r0 + lo) * 64 + kk * 16 + 8 * hh);
    f32x16 sc = zero16();
#pragma unroll
    for (int kk = 0; kk < 4; kk++) sc = mfma32(kf[kk], qf[kk], sc);

    int mbase = l0 - r0 + 992;  // E-row base of 63-wide band (pad to 64)
#pragma unroll
    for (int nf = 0; nf < 2; nf++) {
      bf16x8 ef[4];
#pragma unroll
      for (int kk = 0; kk < 4; kk++)
        ef[kk] = *(const bf16x8*)(eg + (long)(mbase + nf * 32 + lo) * 64 +
                                  kk * 16 + 8 * hh);
      f32x16 uu = zero16(), vv = zero16();
#pragma unroll
      for (int kk = 0; kk < 4; kk++) uu = mfma32(qf[kk], ef[kk], uu);
#pragma unroll
      for (int kk = 0; kk < 4; kk++) vv = mfma32(kf[kk], ef[kk], vv);
      int j = nf * 32 + lo;
#pragma unroll
      for (int i = 0; i < 16; i++) {
        int dl = (i & 3) + 8 * (i >> 2) + 4 * hh;
        Up[dl * 64 + j] = f2bf(uu[i]);
        Vp[dl * 64 + j] = f2bf(vv[i]);
      }
    }
    LGKM_FENCE();

    float pmax = -1e30f;
#pragma unroll
    for (int i = 0; i < 16; i++) {
      int rr = (i & 3) + 8 * (i >> 2) + 4 * hh;
      int jb = 31 + lo - rr;
      float ubv = bf2f(Up[lo * 64 + jb]);
      float vbv = bf2f(Vp[rr * 64 + jb]);
      float v = (sc[i] + ubv + vbv) * inv + mp[r0 + rr];
      sc[i] = v;
      pmax = fmaxf(pmax, v);
    }
    pmax = fmaxf(pmax, __shfl_xor(pmax, 32));
    float mnew = fmaxf(m_run, pmax);
    float alpha = __expf(m_run - mnew);
    m_run = mnew;
    float tsum = 0.f;
#pragma unroll
    for (int i = 0; i < 16; i++) {
      float p = __expf(sc[i] - mnew);
      sc[i] = p;
      tsum += p;
    }
    tsum += __shfl_xor(tsum, 32);
    s_run = s_run * alpha + tsum;
    if (hh == 0) Sp[lo] = alpha;
    LGKM_FENCE();
#pragma unroll
    for (int i = 0; i < 16; i++) {
      float a = Sp[(i & 3) + 8 * (i >> 2) + 4 * hh];
      cx0[i] *= a;
      cx1[i] *= a;
    }
    bf16x8 pA[2];
#pragma unroll
    for (int kk = 0; kk < 2; kk++) {
      unsigned a01 = pack2(sc[8 * kk + 0], sc[8 * kk + 1]);
      unsigned a23 = pack2(sc[8 * kk + 2], sc[8 * kk + 3]);
      unsigned b01 = pack2(sc[8 * kk + 4], sc[8 * kk + 5]);
      unsigned b23 = pack2(sc[8 * kk + 6], sc[8 * kk + 7]);
      unsigned c0a = (unsigned)__shfl((int)a01, lo);
      unsigned c0b = (unsigned)__shfl((int)b01, lo);
      unsigned c1a = (unsigned)__shfl((int)a23, lo);
      unsigned c1b = (unsigned)__shfl((int)b23, lo);
      unsigned c2a = (unsigned)__shfl((int)a01, lo + 32);
      unsigned c2b = (unsigned)__shfl((int)b01, lo + 32);
      unsigned c3a = (unsigned)__shfl((int)a23, lo + 32);
      unsigned c3b = (unsigned)__shfl((int)b23, lo + 32);
      pA[kk] = mk8(hh ? c0b : c0a, hh ? c1b : c1a, hh ? c2b : c2a,
                   hh ? c3b : c3a);
    }
#pragma unroll
    for (int nf = 0; nf < 2; nf++) {
#pragma unroll
      for (int kk = 0; kk < 2; kk++) {
        bf16x8 vf = *(const bf16x8*)(vp + (long)(nf * 32 + lo) * S_ + r0 +
                                     kk * 16 + 8 * hh);
        if (nf == 0)
          cx0 = mfma32(pA[kk], vf, cx0);
        else
          cx1 = mfma32(pA[kk], vf, cx1);
      }
    }
  }
  // write unnormalized numerator + (m,s)
#pragma unroll
  for (int nf = 0; nf < 2; nf++) {
#pragma unroll
    for (int i = 0; i < 16; i++) {
      int rr = (i & 3) + 8 * (i >> 2) + 4 * hh;
      long pidx = ((long)bh * 1024 + l0 + rr) * 64 + nf * 32 + lo;
      Pp[pidx] = f2bf(nf ? cx1[i] : cx0[i]);
    }
  }
  if (hh == 0) msp[bh * 1024 + l0 + lo] = make_float2(m_run, s_run);
}

// ---------------------------------------------------------------------------
// Enc cross-attention (verified structure) + epilogue merging the two
// self-attn partials: ctx = merge(P0,P1) + enc_ctx, emits bf16.
// ---------------------------------------------------------------------------
__global__ __launch_bounds__(256) void k_attn_enc(
    const u16* __restrict__ qg, const u16* __restrict__ kg,
    const u16* __restrict__ vTg, const u16* __restrict__ P0,
    const u16* __restrict__ P1, const float2* __restrict__ ms0,
    const float2* __restrict__ ms1, u16* __restrict__ ctx_bf) {
  __shared__ float Sb[4][32];
  int t = threadIdx.x, w = t >> 6, lane = t & 63;
  int lo = lane & 31, hh = lane >> 5;
  int bh = blockIdx.y, bb = bh >> 4, h = bh & 15;
  int l0 = blockIdx.x * 128 + w * 32;
  const u16* qp = qg + (long)bh * S_ * 64;
  const u16* kp = kg + (long)bh * 512 * 64;
  const u16* vp = vTg + (long)bh * 64 * 512;
  float* Sp = Sb[w];

  bf16x8 qf[4];
#pragma unroll
  for (int kk = 0; kk < 4; kk++)
    qf[kk] = *(const bf16x8*)(qp + (l0 + lo) * 64 + kk * 16 + 8 * hh);

  f32x16 cx0 = zero16(), cx1 = zero16();
  float m_run = -1e30f, s_run = 0.f;
  const float inv = 0.125f;

  for (int r0 = 0; r0 < 512; r0 += 32) {
    bf16x8 kf[4];
#pragma unroll
    for (int kk = 0; kk < 4; kk++)
      kf[kk] = *(const bf16x8*)(kp + (r0 + lo) * 64 + kk * 16 + 8 * hh);
    f32x16 sc = zero16();
#pragma unroll
    for (int kk = 0; kk < 4; kk++) sc = mfma32(kf[kk], qf[kk], sc);

    float pmax = -1e30f;
#pragma unroll
    for (int i = 0; i < 16; i++) {
      float v = sc[i] * inv;
      sc[i] = v;
      pmax = fmaxf(pmax, v);
    }
    pmax = fmaxf(pmax, __shfl_xor(pmax, 32));
    float mnew = fmaxf(m_run, pmax);
    float alpha = __expf(m_run - mnew);
    m_run = mnew;
    float tsum = 0.f;
#pragma unroll
    for (int i = 0; i < 16; i++) {
      float p = __expf(sc[i] - mnew);
      sc[i] = p;
      tsum += p;
    }
    tsum += __shfl_xor(tsum, 32);
    s_run = s_run * alpha + tsum;
    if (hh == 0) Sp[lo] = alpha;
    LGKM_FENCE();
#pragma unroll
    for (int i = 0; i < 16; i++) {
      float a = Sp[(i & 3) + 8 * (i >> 2) + 4 * hh];
      cx0[i] *= a;
      cx1[i] *= a;
    }
    bf16x8 pA[2];
#pragma unroll
    for (int kk = 0; kk < 2; kk++) {
      unsigned a01 = pack2(sc[8 * kk + 0], sc[8 * kk + 1]);
      unsigned a23 = pack2(sc[8 * kk + 2], sc[8 * kk + 3]);
      unsigned b01 = pack2(sc[8 * kk + 4], sc[8 * kk + 5]);
      unsigned b23 = pack2(sc[8 * kk + 6], sc[8 * kk + 7]);
      unsigned c0a = (unsigned)__shfl((int)a01, lo);
      unsigned c0b = (unsigned)__shfl((int)b01, lo);
      unsigned c1a = (unsigned)__shfl((int)a23, lo);
      unsigned c1b = (unsigned)__shfl((int)b23, lo);
      unsigned c2a = (unsigned)__shfl((int)a01, lo + 32);
      unsigned c2b = (unsigned)__shfl((int)b01, lo + 32);
      unsigned c3a = (unsigned)__shfl((int)a23, lo + 32);
      unsigned c3b = (unsigned)__shfl((int)b23, lo + 32);
      pA[kk] = mk8(hh ? c0b : c0a, hh ? c1b : c1a, hh ? c2b : c2a,
                   hh ? c3b : c3a);
    }
#pragma unroll
    for (int nf = 0; nf < 2; nf++) {
#pragma unroll
      for (int kk = 0; kk < 2; kk++) {
        bf16x8 vf = *(const bf16x8*)(vp + (long)(nf * 32 + lo) * 512 + r0 +
                                     kk * 16 + 8 * hh);
        if (nf == 0)
          cx0 = mfma32(pA[kk], vf, cx0);
        else
          cx1 = mfma32(pA[kk], vf, cx1);
      }
    }
  }
  if (hh == 0) Sp[lo] = 1.f / s_run;
  LGKM_FENCE();
  const float2* m0p = ms0 + (long)bh * 1024;
  const float2* m1p = ms1 + (long)bh * 1024;
#pragma unroll
  for (int i = 0; i < 16; i++) {
    int rr = (i & 3) + 8 * (i >> 2) + 4 * hh;
    int l = l0 + rr;
    float2 a0 = m0p[l], a1 = m1p[l];
    float Mx = fmaxf(a0.x, a1.x);
    float w0 = __expf(a0.x - Mx), w1 = __expf(a1.x - Mx);
    float dn = 1.f / (w0 * a0.y + w1 * a1.y);
    float sv = Sp[rr];
#pragma unroll
    for (int nf = 0; nf < 2; nf++) {
      long pidx = ((long)bh * 1024 + l) * 64 + nf * 32 + lo;
      float nself = w0 * bf2f(P0[pidx]) + w1 * bf2f(P1[pidx]);
      float val = (nf ? cx1[i] : cx0[i]) * sv + nself * dn;
      ctx_bf[((long)(bb * 1024 + l)) * 1024 + h * 64 + nf * 32 + lo] =
          f2bf(val);
    }
  }
}

// ---------------------------------------------------------------------------
// Row LayerNorm: 1 block per row of y[4096][1024].
// ---------------------------------------------------------------------------
__global__ __launch_bounds__(256) void k_ln(const float* __restrict__ y,
                                            const float* __restrict__ g,
                                            const float* __restrict__ bta,
                                            float* __restrict__ out) {
  int row = blockIdx.x, t = threadIdx.x;
  const float* yr = y + (long)row * 1024;
  float4 v = *(const float4*)(yr + t * 4);
  float s = v.x + v.y + v.z + v.w;
  float q = v.x * v.x + v.y * v.y + v.z * v.z + v.w * v.w;
#pragma unroll
  for (int off = 1; off < 64; off <<= 1) {
    s += __shfl_xor(s, off);
    q += __shfl_xor(q, off);
  }
  __shared__ float ss[4], qq[4];
  if ((t & 63) == 0) {
    ss[t >> 6] = s;
    qq[t >> 6] = q;
  }
  __syncthreads();
  s = ss[0] + ss[1] + ss[2] + ss[3];
  q = qq[0] + qq[1] + qq[2] + qq[3];
  float mu = s * (1.f / 1024.f);
  float var = q * (1.f / 1024.f) - mu * mu;
  float rinv = rsqrtf(var + 1e-12f);
  float4 gv = *(const float4*)(g + t * 4);
  float4 bv = *(const float4*)(bta + t * 4);
  float4 o;
  o.x = (v.x - mu) * rinv * gv.x + bv.x;
  o.y = (v.y - mu) * rinv * gv.y + bv.y;
  o.z = (v.z - mu) * rinv * gv.z + bv.z;
  o.w = (v.w - mu) * rinv * gv.w + bv.w;
  *(float4*)(out + (long)row * 1024 + t * 4) = o;
}

// ---------------------------------------------------------------------------
extern "C" void kernel_launch(void* const* d_in, const int* in_sizes, int n_in,
                              void* d_out, int out_size, void* d_ws,
                              size_t ws_size, hipStream_t stream) {
  (void)in_sizes; (void)n_in; (void)out_size; (void)ws_size;
  const float* hs   = (const float*)d_in[0];
  const float* mask = (const float*)d_in[1];
  const float* enc  = (const float*)d_in[2];
  const float* Wq   = (const float*)d_in[3];
  const float* bq   = (const float*)d_in[4];
  const float* Wk   = (const float*)d_in[5];
  const float* bk   = (const float*)d_in[6];
  const float* Wv   = (const float*)d_in[7];
  const float* bv   = (const float*)d_in[8];
  const float* Wfk  = (const float*)d_in[9];
  const float* bfk  = (const float*)d_in[10];
  const float* Wfv  = (const float*)d_in[11];
  const float* bfv  = (const float*)d_in[12];
  const float* de   = (const float*)d_in[13];
  const float* Wo   = (const float*)d_in[14];
  const float* bo   = (const float*)d_in[15];
  const float* lng  = (const float*)d_in[16];
  const float* lnb  = (const float*)d_in[17];

  char* ws = (char*)d_ws;
  // 63.2 MB total. wq..wv and wfk..wfv are stacked-contiguous for fused GEMMs.
  u16* hs_bf  = (u16*)(ws + 0L);
  u16* enc_bf = (u16*)(ws + 8388608L);
  u16* wq_bf  = (u16*)(ws + 10485760L);  // stacked qkv [3072][1024]
  u16* wk_bf  = (u16*)(ws + 12582912L);
  u16* wv_bf  = (u16*)(ws + 14680064L);
  u16* wo_bf  = (u16*)(ws + 16777216L);
  u16* wfk_bf = (u16*)(ws + 18874368L);  // stacked fkv [2048][512]
  u16* wfv_bf = (u16*)(ws + 19922944L);
  u16* e_bf   = (u16*)(ws + 20971520L);  // 2048x64 (row 2047 zeroed)
  u16* q_bf   = (u16*)(ws + 21233664L);  // [B,H,S,64]
  u16* k_bf   = (u16*)(ws + 29622272L);  // [B,H,S,64]
  u16* vT_bf  = (u16*)(ws + 38010880L);  // [B,H,64,S]
  u16* fk_bf  = (u16*)(ws + 46399488L);  // [B,H,SE,64]
  u16* fvT_bf = (u16*)(ws + 50593792L);  // [B,H,64,SE]
  u16* ctx_bf = (u16*)(ws + 54788096L);  // ends 63,176,704
  // Aliases (temporally disjoint):
  u16* P0     = (u16*)(ws + 0L);         // self partial 0 (over hs/enc)
  u16* P1     = (u16*)(ws + 8388608L);   // self partial 1 (over wqkv)
  float2* ms0 = (float2*)(ws + 18874368L);  // over dead wfk (after FKV GEMM)
  float2* ms1 = (float2*)(ws + 19398656L);
  float* y    = (float*)(ws + 0L);       // out-proj dest (over P0/P1)

  k_convert<<<10368, 256, 0, stream>>>(hs, enc, Wq, Wk, Wv, Wo, Wfk, Wfv, de,
                                       hs_bf, enc_bf, wq_bf, wk_bf, wv_bf,
                                       wo_bf, wfk_bf, wfv_bf, e_bf);

  dim3 blk(256);
  // QKV fused: M=4096, N=3072 (stacked), K=1024
  k_gemm_proj<<<dim3(24, 64), blk, 0, stream>>>(
      hs_bf, wq_bf, bq, bk, bv, q_bf, k_bf, vT_bf, 1024, 1024, 10, 2);
  // FK/FV fused: M=2048, N=2048 (stacked), K=512
  k_gemm_proj<<<dim3(16, 32), blk, 0, stream>>>(
      enc_bf, wfk_bf, bfk, bfv, bfv, fk_bf, fvT_bf, fvT_bf, 512, 512, 9, 1);

  k_attn_self<<<dim3(8, 64, 2), blk, 0, stream>>>(q_bf, k_bf, vT_bf, e_bf,
                                                  mask, P0, P1, ms0, ms1);
  k_attn_enc<<<dim3(8, 64), blk, 0, stream>>>(q_bf, fk_bf, fvT_bf, P0, P1,
                                              ms0, ms1, ctx_bf);

  k_gemm_out<<<dim3(8, 64), blk, 0, stream>>>(ctx_bf, wo_bf, bo, y, hs, 1024);
  k_ln<<<4096, blk, 0, stream>>>(y, lng, lnb, (float*)d_out);
}